// Round 3
// baseline (97.928 us; speedup 1.0000x reference)
//
#include <hip/hip_runtime.h>
#include <math.h>

// SimilarityLoss: loss = w * mean((sim_o - sim_t)^2), sims are N x N cosine-sim
// grams with zeroed diagonal. Identity (diagonal mask is a no-op: both diags == 1):
//   ||On On^T - Tn Tn^T||_F^2 = ||On^T On||^2 + ||Tn^T Tn||^2 - 2 ||On^T Tn||^2
// -> three 256x256 grams instead of two 8192x8192 sims (21x fewer FLOPs).
// Output: single FLOAT32 scalar (round-2 evidence: harness decodes d_out as fp32).

#define N_ROWS 8192
#define DDIM   256
#define NCHUNK 16
#define KCHUNK (N_ROWS / NCHUNK)   // 512
#define KT     16
#define TILE   64

// ws layout (floats):
//   [0, N_ROWS)         : inv_o  (1/max(||o_k||, eps))
//   [N_ROWS, 2*N_ROWS)  : inv_t
//   [2*N_ROWS, +3*D*D)  : grams: goo, gtt, got
//   [SCALAR_OFF]        : float accumulator for the Frobenius sum
#define GRAM_OFF   (2 * N_ROWS)
#define GRAM_ELEMS (3 * DDIM * DDIM)
#define SCALAR_OFF (GRAM_OFF + GRAM_ELEMS)

__global__ void zero_kernel(float* __restrict__ ws) {
    int idx = blockIdx.x * blockDim.x + threadIdx.x;
    if (idx < GRAM_ELEMS) ws[GRAM_OFF + idx] = 0.0f;
    if (idx == 0) ws[SCALAR_OFF] = 0.0f;
}

// One wave (64 lanes) per row; waves [0,N) -> O rows, [N,2N) -> T rows.
__global__ void norms_kernel(const float* __restrict__ O,
                             const float* __restrict__ T,
                             float* __restrict__ ws) {
    int wave = (blockIdx.x * blockDim.x + threadIdx.x) >> 6;
    int lane = threadIdx.x & 63;
    const float* src;
    float* dst;
    int row;
    if (wave < N_ROWS) { src = O; row = wave;          dst = ws; }
    else               { src = T; row = wave - N_ROWS; dst = ws + N_ROWS; }
    float4 v = *reinterpret_cast<const float4*>(src + (size_t)row * DDIM + lane * 4);
    float ss = v.x * v.x + v.y * v.y + v.z * v.z + v.w * v.w;
    #pragma unroll
    for (int off = 32; off > 0; off >>= 1) ss += __shfl_down(ss, off);
    if (lane == 0) dst[row] = 1.0f / fmaxf(sqrtf(ss), 1e-8f);
}

// Gram GEMM: G_g[a,b] += sum_{k in chunk} A[k,a]*invA[k] * B[k,b]*invB[k]
// blockIdx.x/y: 64x64 output tile; blockIdx.z: gram (z%3) x K-chunk (z/3).
// g=0: A=O,B=O   g=1: A=T,B=T   g=2: A=O,B=T   (round-1 bug: g=1 had B=O!)
__global__ __launch_bounds__(256) void gram_kernel(const float* __restrict__ O,
                                                   const float* __restrict__ T,
                                                   float* __restrict__ ws) {
    const float* inv_o = ws;
    const float* inv_t = ws + N_ROWS;
    float* grams = ws + GRAM_OFF;

    int g = blockIdx.z % 3;        // 0: oo, 1: tt, 2: ot
    int chunk = blockIdx.z / 3;
    const float* A = (g == 1) ? T : O;
    const float* B = (g == 0) ? O : T;
    const float* invA = (g == 1) ? inv_t : inv_o;
    const float* invB = (g == 0) ? inv_o : inv_t;
    float* G = grams + g * (DDIM * DDIM);

    int m0 = blockIdx.x * TILE;
    int n0 = blockIdx.y * TILE;
    int k0 = chunk * KCHUNK;

    __shared__ __align__(16) float As[KT][TILE];
    __shared__ __align__(16) float Bs[KT][TILE];

    int tid = threadIdx.x;
    int tx = tid & 15;
    int ty = tid >> 4;
    int lm = tid & 63;   // column within tile for staging
    int lk = tid >> 6;   // k row 0..3, strided by 4

    float acc[4][4] = {};

    for (int kt = 0; kt < KCHUNK; kt += KT) {
        __syncthreads();
        #pragma unroll
        for (int i = 0; i < KT; i += 4) {
            int kk = lk + i;
            int krow = k0 + kt + kk;
            As[kk][lm] = A[(size_t)krow * DDIM + m0 + lm] * invA[krow];
            Bs[kk][lm] = B[(size_t)krow * DDIM + n0 + lm] * invB[krow];
        }
        __syncthreads();
        #pragma unroll
        for (int kk = 0; kk < KT; ++kk) {
            float4 av = *reinterpret_cast<const float4*>(&As[kk][ty * 4]);
            float4 bv = *reinterpret_cast<const float4*>(&Bs[kk][tx * 4]);
            float a[4] = {av.x, av.y, av.z, av.w};
            float b[4] = {bv.x, bv.y, bv.z, bv.w};
            #pragma unroll
            for (int i = 0; i < 4; ++i)
                #pragma unroll
                for (int j = 0; j < 4; ++j)
                    acc[i][j] = fmaf(a[i], b[j], acc[i][j]);
        }
    }

    #pragma unroll
    for (int i = 0; i < 4; ++i)
        #pragma unroll
        for (int j = 0; j < 4; ++j)
            atomicAdd(&G[(size_t)(m0 + ty * 4 + i) * DDIM + (n0 + tx * 4 + j)],
                      acc[i][j]);
}

// Frobenius combine: sum(+goo^2 + gtt^2 - 2*got^2) -> ws[SCALAR_OFF] (float)
__global__ void reduce_kernel(float* __restrict__ ws) {
    const float* grams = ws + GRAM_OFF;
    int idx = blockIdx.x * blockDim.x + threadIdx.x;   // float4 index
    float4 v = reinterpret_cast<const float4*>(grams)[idx];
    float s = v.x * v.x + v.y * v.y + v.z * v.z + v.w * v.w;
    int g = (idx * 4) / (DDIM * DDIM);
    s *= (g == 2) ? -2.0f : 1.0f;
    #pragma unroll
    for (int off = 32; off > 0; off >>= 1) s += __shfl_down(s, off);
    __shared__ float wsum[4];
    int lane = threadIdx.x & 63;
    int w = threadIdx.x >> 6;
    if (lane == 0) wsum[w] = s;
    __syncthreads();
    if (threadIdx.x == 0) {
        atomicAdd(&ws[SCALAR_OFF], wsum[0] + wsum[1] + wsum[2] + wsum[3]);
    }
}

// Final: out (float32) = acc * weight / N^2
__global__ void finalize_kernel(const float* __restrict__ ws,
                                const float* __restrict__ weight,
                                float* __restrict__ out) {
    float scale = weight[0] / ((float)N_ROWS * (float)N_ROWS);
    out[0] = ws[SCALAR_OFF] * scale;
}

extern "C" void kernel_launch(void* const* d_in, const int* in_sizes, int n_in,
                              void* d_out, int out_size, void* d_ws, size_t ws_size,
                              hipStream_t stream) {
    const float* O = (const float*)d_in[0];
    const float* T = (const float*)d_in[1];
    const float* W = (const float*)d_in[2];
    float* out = (float*)d_out;
    float* ws = (float*)d_ws;

    // 1. zero grams + scalar accumulator
    zero_kernel<<<(GRAM_ELEMS + 255) / 256, 256, 0, stream>>>(ws);

    // 2. per-row inverse norms (one wave per row, 2N rows total)
    norms_kernel<<<(2 * N_ROWS) / 4, 256, 0, stream>>>(O, T, ws);

    // 3. three grams, K split into NCHUNK chunks -> 4*4*3*16 = 768 blocks
    dim3 ggrid(DDIM / TILE, DDIM / TILE, 3 * NCHUNK);
    gram_kernel<<<ggrid, 256, 0, stream>>>(O, T, ws);

    // 4. Frobenius combine -> ws scalar (float)
    reduce_kernel<<<(GRAM_ELEMS / 4) / 256, 256, 0, stream>>>(ws);

    // 5. scale + write fp32 output
    finalize_kernel<<<1, 1, 0, stream>>>(ws, W, out);
}

// Round 4
// 33.172 us; speedup vs baseline: 2.9522x; 2.9522x over previous
//
#include <hip/hip_runtime.h>
#include <hip/hip_bf16.h>
#include <math.h>

// loss = w * mean((sim_o - sim_t)^2)  with  ||OO^T - TT^T||^2 =
//   ||O^T O||^2 + ||T^T T||^2 - 2||O^T T||^2  (diag mask is a no-op).
// Three 256x256 feature-grams via bf16 MFMA; non-atomic bf16 partials
// per K-chunk (round-3 counters: gram atomics cost ~90MB HBM traffic).

#define N_ROWS 8192
#define DDIM   256
#define NC     16               // K chunks
#define KC     (N_ROWS / NC)    // 512 rows / chunk
#define KS     64               // k rows staged per iter
#define ITERS  (KC / KS)        // 8
#define TW     64               // output tile width
#define PART_STRIDE (3 * 16 * 4096)   // ushorts per chunk = 196608

// ws layout: float[0] = scalar acc; float[16..16+8192) inv_o;
// [16+8192..16+16384) inv_t; then bf16 partials: NC * 196608 ushorts.
#define INV_O_OFF 16
#define INV_T_OFF (16 + N_ROWS)
#define PART_FOFF (16 + 2 * N_ROWS)

typedef __bf16 bf16x8 __attribute__((ext_vector_type(8)));
typedef short  short8 __attribute__((ext_vector_type(8)));
typedef float  f32x16 __attribute__((ext_vector_type(16)));

__device__ inline unsigned short f2bu(float x) {
    __hip_bfloat16 h = __float2bfloat16(x);
    return __builtin_bit_cast(unsigned short, h);
}
__device__ inline float u2f(unsigned short u) {
    unsigned int v = ((unsigned int)u) << 16;
    return __builtin_bit_cast(float, v);
}

// ---- 1. per-row inverse norms (wave per row); also zeroes the scalar ----
__global__ void norms_kernel(const float* __restrict__ O,
                             const float* __restrict__ T,
                             float* __restrict__ ws) {
    if (blockIdx.x == 0 && threadIdx.x == 0) ws[0] = 0.0f;
    int wave = (blockIdx.x * blockDim.x + threadIdx.x) >> 6;
    int lane = threadIdx.x & 63;
    const float* src;
    float* dst;
    int row;
    if (wave < N_ROWS) { src = O; row = wave;          dst = ws + INV_O_OFF; }
    else               { src = T; row = wave - N_ROWS; dst = ws + INV_T_OFF; }
    float4 v = *reinterpret_cast<const float4*>(src + (size_t)row * DDIM + lane * 4);
    float ss = v.x * v.x + v.y * v.y + v.z * v.z + v.w * v.w;
    #pragma unroll
    for (int off = 32; off > 0; off >>= 1) ss += __shfl_down(ss, off);
    if (lane == 0) dst[row] = 1.0f / fmaxf(sqrtf(ss), 1e-8f);
}

// ---- 2. MFMA gram kernel ----
// grid: 256 blocks = 16 tiles (tm,tn of 64x64) x 16 K-chunks. 256 thr = 4 waves
// (2x2), each wave one 32x32 mfma position for grams OO, TT, OT.
// LDS slabs [k][feat] bf16, 4 slabs {O_m, O_n, T_m, T_n}, double-buffered.
// Swizzle: elem index k*64 + (f ^ (((k>>3)&1)<<5)).
__global__ __launch_bounds__(256) void gram_kernel(const float* __restrict__ O,
                                                   const float* __restrict__ T,
                                                   float* __restrict__ ws) {
    const float* inv_o = ws + INV_O_OFF;
    const float* inv_t = ws + INV_T_OFF;
    unsigned short* part = (unsigned short*)(ws + PART_FOFF);

    int bid = blockIdx.x;
    int ti = bid & 15, c = bid >> 4;
    int tm = ti >> 2, tn = ti & 3;
    int tid = threadIdx.x;
    int lane = tid & 63, wid = tid >> 6;
    int wm = wid >> 1, wn = wid & 1;
    int k0 = c * KC;

    __shared__ unsigned short lds[2][4][KS * TW];   // 64 KiB

    float4 rv[4][4];   // [q][slab] staged fp32
    float  iv[4][2];   // [q][O/T] inv norms

    f32x16 acc_oo, acc_tt, acc_ot;
    #pragma unroll
    for (int e = 0; e < 16; ++e) { acc_oo[e] = 0.f; acc_tt[e] = 0.f; acc_ot[e] = 0.f; }

    auto stage_load = [&](int it) {
        int kb = k0 + it * KS;
        #pragma unroll
        for (int q = 0; q < 4; ++q) {
            int u = tid + q * 256;          // [0,1024)
            int k = u >> 4;                 // 0..63
            int f0 = (u & 15) * 4;
            int row = kb + k;
            iv[q][0] = inv_o[row];
            iv[q][1] = inv_t[row];
            #pragma unroll
            for (int s = 0; s < 4; ++s) {
                const float* M = (s >> 1) ? T : O;
                int ft = (s & 1) ? tn : tm;
                rv[q][s] = *reinterpret_cast<const float4*>(
                    M + (size_t)row * DDIM + ft * TW + f0);
            }
        }
    };
    auto stage_write = [&](int buf) {
        #pragma unroll
        for (int q = 0; q < 4; ++q) {
            int u = tid + q * 256;
            int k = u >> 4;
            int f0 = (u & 15) * 4;
            int fx = f0 ^ (((k >> 3) & 1) << 5);
            #pragma unroll
            for (int s = 0; s < 4; ++s) {
                float sc = iv[q][s >> 1];
                float4 v = rv[q][s];
                ushort4 w;
                w.x = f2bu(v.x * sc); w.y = f2bu(v.y * sc);
                w.z = f2bu(v.z * sc); w.w = f2bu(v.w * sc);
                *reinterpret_cast<ushort4*>(&lds[buf][s][k * TW + fx]) = w;
            }
        }
    };
    auto ldfrag = [&](const unsigned short* sl, int kb, int fx) -> bf16x8 {
        short8 t;
        #pragma unroll
        for (int j = 0; j < 8; ++j) t[j] = (short)sl[(kb + j) * TW + fx];
        return __builtin_bit_cast(bf16x8, t);
    };

    stage_load(0);
    stage_write(0);
    __syncthreads();

    for (int it = 0; it < ITERS; ++it) {
        int cur = it & 1;
        if (it + 1 < ITERS) stage_load(it + 1);   // overlap HBM/L3 latency
        #pragma unroll
        for (int kk = 0; kk < 4; ++kk) {
            int kb = kk * 16 + ((lane >> 5) << 3);      // k base, mult of 8
            int sw = ((kb >> 3) & 1) << 5;
            int fmx = ((wm << 5) + (lane & 31)) ^ sw;
            int fnx = ((wn << 5) + (lane & 31)) ^ sw;
            bf16x8 ao = ldfrag(&lds[cur][0][0], kb, fmx);
            bf16x8 bo = ldfrag(&lds[cur][1][0], kb, fnx);
            bf16x8 at = ldfrag(&lds[cur][2][0], kb, fmx);
            bf16x8 bt = ldfrag(&lds[cur][3][0], kb, fnx);
            acc_oo = __builtin_amdgcn_mfma_f32_32x32x16_bf16(ao, bo, acc_oo, 0, 0, 0);
            acc_tt = __builtin_amdgcn_mfma_f32_32x32x16_bf16(at, bt, acc_tt, 0, 0, 0);
            acc_ot = __builtin_amdgcn_mfma_f32_32x32x16_bf16(ao, bt, acc_ot, 0, 0, 0);
        }
        if (it + 1 < ITERS) stage_write(cur ^ 1);
        __syncthreads();
    }

    // partial write: C/D layout (m74/m101): col=lane&31, row=(reg&3)+8*(reg>>2)+4*(lane>>5)
    unsigned int tb = (unsigned int)(c * 16 + ti) * 3;
    #pragma unroll
    for (int reg = 0; reg < 16; ++reg) {
        int row = (reg & 3) + 8 * (reg >> 2) + ((lane >> 5) << 2);
        int col = lane & 31;
        int idx = (wm * 32 + row) * TW + (wn * 32 + col);
        part[(size_t)(tb + 0) * 4096 + idx] = f2bu(acc_oo[reg]);
        part[(size_t)(tb + 1) * 4096 + idx] = f2bu(acc_tt[reg]);
        part[(size_t)(tb + 2) * 4096 + idx] = f2bu(acc_ot[reg]);
    }
}

// ---- 3. fused partial-sum + Frobenius combine -> ws[0] ----
__global__ void reduce_kernel(float* __restrict__ ws) {
    const unsigned short* part = (const unsigned short*)(ws + PART_FOFF);
    int gid = blockIdx.x * blockDim.x + threadIdx.x;   // 49152 threads
    int base = gid * 4;
    float s0 = 0.f, s1 = 0.f, s2 = 0.f, s3 = 0.f;
    for (int cc = 0; cc < NC; ++cc) {
        ushort4 u = *reinterpret_cast<const ushort4*>(&part[(size_t)cc * PART_STRIDE + base]);
        s0 += u2f(u.x); s1 += u2f(u.y); s2 += u2f(u.z); s3 += u2f(u.w);
    }
    int g = (base >> 12) % 3;   // layout: (ti*3+g)*4096 + e
    float s = s0 * s0 + s1 * s1 + s2 * s2 + s3 * s3;
    if (g == 2) s = -2.0f * s;
    #pragma unroll
    for (int off = 32; off > 0; off >>= 1) s += __shfl_down(s, off);
    __shared__ float wsum[4];
    int lane = threadIdx.x & 63, w = threadIdx.x >> 6;
    if (lane == 0) wsum[w] = s;
    __syncthreads();
    if (threadIdx.x == 0)
        atomicAdd(&ws[0], wsum[0] + wsum[1] + wsum[2] + wsum[3]);
}

// ---- 4. scale + fp32 scalar out ----
__global__ void finalize_kernel(const float* __restrict__ ws,
                                const float* __restrict__ weight,
                                float* __restrict__ out) {
    out[0] = ws[0] * weight[0] / ((float)N_ROWS * (float)N_ROWS);
}

extern "C" void kernel_launch(void* const* d_in, const int* in_sizes, int n_in,
                              void* d_out, int out_size, void* d_ws, size_t ws_size,
                              hipStream_t stream) {
    const float* O = (const float*)d_in[0];
    const float* T = (const float*)d_in[1];
    const float* W = (const float*)d_in[2];
    float* out = (float*)d_out;
    float* ws = (float*)d_ws;

    norms_kernel<<<(2 * N_ROWS) / 4, 256, 0, stream>>>(O, T, ws);
    gram_kernel<<<16 * NC, 256, 0, stream>>>(O, T, ws);
    reduce_kernel<<<(PART_STRIDE / 4) / 256, 256, 0, stream>>>(ws);
    finalize_kernel<<<1, 1, 0, stream>>>(ws, W, out);
}

// Round 5
// 31.391 us; speedup vs baseline: 3.1196x; 1.0567x over previous
//
#include <hip/hip_runtime.h>
#include <hip/hip_bf16.h>
#include <math.h>

// loss = w * mean((sim_o - sim_t)^2);  ||OO^T - TT^T||^2 =
//   ||O^T O||^2 + ||T^T T||^2 - 2||O^T T||^2  (diag mask is a no-op).
// Pipeline: (1) one-time normalize + bf16 + transpose -> Obt/Tbt [f][k];
// (2) MFMA gram kernel: global_load_lds staging (swizzled src), ds_read_b128
// fragments; (3) partial-sum + Frobenius combine; (4) fp32 scalar out.

#define N_ROWS 8192
#define DDIM   256
#define NC     32                  // K chunks
#define KC     (N_ROWS / NC)       // 256 rows / chunk
#define KS     64                  // k rows staged per iter
#define NITER  (KC / KS)           // 4
#define PART_STRIDE 196608         // 3 grams * 16 tiles * 4096 ushorts per chunk

// ushort-space offsets into ws (ws[0..15] floats: [0]=scalar acc)
#define OBT_UOFF  32
#define MAT_USZ   (DDIM * N_ROWS)            // 2,097,152 ushorts per matrix
#define PART_UOFF (OBT_UOFF + 2 * MAT_USZ)

typedef __bf16 bf16x8 __attribute__((ext_vector_type(8)));
typedef short  short8 __attribute__((ext_vector_type(8)));
typedef float  f32x16 __attribute__((ext_vector_type(16)));
typedef unsigned int u32;

__device__ inline unsigned short f2bu(float x) {
    __hip_bfloat16 h = __float2bfloat16(x);
    return __builtin_bit_cast(unsigned short, h);
}
__device__ inline float u2f(unsigned short u) {
    unsigned int v = ((unsigned int)u) << 16;
    return __builtin_bit_cast(float, v);
}
__device__ inline void gload_lds16(const void* g, void* l) {
    __builtin_amdgcn_global_load_lds(
        (const __attribute__((address_space(1))) u32*)g,
        (__attribute__((address_space(3))) u32*)l, 16, 0, 0);
}

// ---- 1. normalize + bf16 + transpose: O,T (fp32 [k][f]) -> Obt,Tbt (bf16 [f][k])
// 512 blocks: (b&1) matrix, (b>>1) 32-row k-slab. Wave per row-load (coalesced
// 1KB/row); LDS-staged transpose; thread f writes its 32 k contiguous.
__global__ __launch_bounds__(256) void transpose_kernel(const float* __restrict__ O,
                                                        const float* __restrict__ T,
                                                        float* __restrict__ ws) {
    if (blockIdx.x == 0 && threadIdx.x == 0) ws[0] = 0.0f;
    int b = blockIdx.x;
    const float* src = (b & 1) ? T : O;
    unsigned short* dst = (unsigned short*)ws + OBT_UOFF + (size_t)(b & 1) * MAT_USZ;
    int kb = (b >> 1) * 32;
    __shared__ unsigned short lt[32][260];   // +pad to spread banks
    int w = threadIdx.x >> 6, l = threadIdx.x & 63;
    #pragma unroll
    for (int j = 0; j < 8; ++j) {
        int r = j * 4 + w;
        float4 v = *reinterpret_cast<const float4*>(src + (size_t)(kb + r) * DDIM + l * 4);
        float ss = v.x * v.x + v.y * v.y + v.z * v.z + v.w * v.w;
        #pragma unroll
        for (int off = 32; off > 0; off >>= 1) ss += __shfl_xor(ss, off);
        float inv = 1.0f / fmaxf(sqrtf(ss), 1e-8f);
        ushort4 u;
        u.x = f2bu(v.x * inv); u.y = f2bu(v.y * inv);
        u.z = f2bu(v.z * inv); u.w = f2bu(v.w * inv);
        *reinterpret_cast<ushort4*>(&lt[r][l * 4]) = u;
    }
    __syncthreads();
    int f = threadIdx.x;
    #pragma unroll
    for (int s = 0; s < 8; ++s) {
        ushort4 u;
        u.x = lt[s * 4 + 0][f]; u.y = lt[s * 4 + 1][f];
        u.z = lt[s * 4 + 2][f]; u.w = lt[s * 4 + 3][f];
        *reinterpret_cast<ushort4*>(&dst[(size_t)f * N_ROWS + kb + s * 4]) = u;
    }
}

// ---- 2. MFMA gram kernel ----
// grid 512 = 16 tiles (4x4 of 64x64) x 32 K-chunks; 4 waves (2x2 of 32x32).
// LDS slabs [f_local 64][k 64] bf16, k-blocks (16B) XOR-swizzled by (f&7);
// swizzle applied by permuting the per-lane GLOBAL src (LDS dest stays linear
// as global_load_lds requires). Fragment = one ds_read_b128.
__global__ __launch_bounds__(256) void gram_kernel(float* __restrict__ ws) {
    const unsigned short* obt = (const unsigned short*)ws + OBT_UOFF;
    unsigned short* part = (unsigned short*)ws + PART_UOFF;

    int bid = blockIdx.x;
    int ti = bid & 15, c = bid >> 4;
    int tm = ti >> 2, tn = ti & 3;
    int tid = threadIdx.x, lane = tid & 63, wid = tid >> 6;
    int wm = wid >> 1, wn = wid & 1;
    int k0 = c * KC;

    __shared__ __align__(16) unsigned short lds[2][4][KS * 64];   // 64 KiB

    f32x16 acc_oo, acc_tt, acc_ot;
    #pragma unroll
    for (int e = 0; e < 16; ++e) { acc_oo[e] = 0.f; acc_tt[e] = 0.f; acc_ot[e] = 0.f; }

    // wave `wid` stages slab wid: {0:O_m, 1:O_n, 2:T_m, 3:T_n}
    int sl = wid;
    int mat = sl >> 1;
    int ft = (sl & 1) ? tn : tm;
    const unsigned short* slab_src =
        obt + (size_t)mat * MAT_USZ + (size_t)(ft * 64) * N_ROWS;
    int frow = lane >> 3;                                // f-row within 8-group
    int swz8 = ((lane & 7) ^ (frow & 7)) * 8;            // inverse == forward (XOR)

    auto stage = [&](int buf, int it) {
        int kb = k0 + it * KS;
        const unsigned short* base = slab_src + kb + (size_t)frow * N_ROWS + swz8;
        unsigned short* ld = &lds[buf][sl][0];
        #pragma unroll
        for (int i = 0; i < 8; ++i)   // instr i: f-rows i*8..i*8+7, 1KB
            gload_lds16(base + (size_t)(i * 8) * N_ROWS, ld + i * 512);
    };

    int fm = wm * 32 + (lane & 31);
    int fn = wn * 32 + (lane & 31);
    int jhalf = lane >> 5;
    auto frag = [&](int buf, int s, int fl, int kk) -> bf16x8 {
        int j0 = kk * 2 + jhalf;                         // 16B k-block index
        const unsigned short* p = &lds[buf][s][fl * 64 + ((j0 ^ (fl & 7)) * 8)];
        return __builtin_bit_cast(bf16x8, *reinterpret_cast<const short8*>(p));
    };

    stage(0, 0);
    __syncthreads();
    int cur = 0;
    for (int it = 0; it < NITER; ++it) {
        if (it + 1 < NITER) stage(cur ^ 1, it + 1);      // async, hidden under MFMA
        #pragma unroll
        for (int kk = 0; kk < 4; ++kk) {
            bf16x8 ao = frag(cur, 0, fm, kk);
            bf16x8 bo = frag(cur, 1, fn, kk);
            bf16x8 at = frag(cur, 2, fm, kk);
            bf16x8 bt = frag(cur, 3, fn, kk);
            acc_oo = __builtin_amdgcn_mfma_f32_32x32x16_bf16(ao, bo, acc_oo, 0, 0, 0);
            acc_tt = __builtin_amdgcn_mfma_f32_32x32x16_bf16(at, bt, acc_tt, 0, 0, 0);
            acc_ot = __builtin_amdgcn_mfma_f32_32x32x16_bf16(ao, bt, acc_ot, 0, 0, 0);
        }
        __syncthreads();   // drains vmcnt+lgkm: buf^1 staged, cur free to reuse
        cur ^= 1;
    }

    // C/D layout (m74/m101): col=lane&31, row=(reg&3)+8*(reg>>2)+4*(lane>>5)
    unsigned int tb = (unsigned int)(c * 16 + ti) * 3;
    #pragma unroll
    for (int reg = 0; reg < 16; ++reg) {
        int row = (reg & 3) + 8 * (reg >> 2) + ((lane >> 5) << 2);
        int col = lane & 31;
        int idx = (wm * 32 + row) * 64 + (wn * 32 + col);
        part[(size_t)(tb + 0) * 4096 + idx] = f2bu(acc_oo[reg]);
        part[(size_t)(tb + 1) * 4096 + idx] = f2bu(acc_tt[reg]);
        part[(size_t)(tb + 2) * 4096 + idx] = f2bu(acc_ot[reg]);
    }
}

// ---- 3. partial-sum over chunks + Frobenius combine -> ws[0] (float) ----
__global__ void reduce_kernel(float* __restrict__ ws) {
    const unsigned short* part = (const unsigned short*)ws + PART_UOFF;
    int gid = blockIdx.x * blockDim.x + threadIdx.x;   // 49152 threads
    int base = gid * 4;
    float s0 = 0.f, s1 = 0.f, s2 = 0.f, s3 = 0.f;
    for (int cc = 0; cc < NC; ++cc) {
        ushort4 u = *reinterpret_cast<const ushort4*>(&part[(size_t)cc * PART_STRIDE + base]);
        s0 += u2f(u.x); s1 += u2f(u.y); s2 += u2f(u.z); s3 += u2f(u.w);
    }
    int g = (base >> 12) % 3;   // within-chunk layout: (ti*3+g)*4096 + e
    float s = s0 * s0 + s1 * s1 + s2 * s2 + s3 * s3;
    if (g == 2) s = -2.0f * s;
    #pragma unroll
    for (int off = 32; off > 0; off >>= 1) s += __shfl_down(s, off);
    __shared__ float wsum[4];
    int lane = threadIdx.x & 63, w = threadIdx.x >> 6;
    if (lane == 0) wsum[w] = s;
    __syncthreads();
    if (threadIdx.x == 0)
        atomicAdd(&ws[0], wsum[0] + wsum[1] + wsum[2] + wsum[3]);
}

// ---- 4. scale + fp32 scalar out ----
__global__ void finalize_kernel(const float* __restrict__ ws,
                                const float* __restrict__ weight,
                                float* __restrict__ out) {
    out[0] = ws[0] * weight[0] / ((float)N_ROWS * (float)N_ROWS);
}

extern "C" void kernel_launch(void* const* d_in, const int* in_sizes, int n_in,
                              void* d_out, int out_size, void* d_ws, size_t ws_size,
                              hipStream_t stream) {
    const float* O = (const float*)d_in[0];
    const float* T = (const float*)d_in[1];
    const float* W = (const float*)d_in[2];
    float* out = (float*)d_out;
    float* ws = (float*)d_ws;

    transpose_kernel<<<512, 256, 0, stream>>>(O, T, ws);
    gram_kernel<<<16 * NC, 256, 0, stream>>>(ws);        // 512 blocks
    reduce_kernel<<<192, 256, 0, stream>>>(ws);
    finalize_kernel<<<1, 1, 0, stream>>>(ws, W, out);
}